// Round 17
// baseline (10736.494 us; speedup 1.0000x reference)
//
#include <hip/hip_runtime.h>

#define T_STEPS 2048
#define NBATCH  1024
#define L2E     1.442695040888963f
#define TILES   4                     // batch-tiles per block

typedef _Float16 f16x8 __attribute__((ext_vector_type(8)));
typedef float    f32x4 __attribute__((ext_vector_type(4)));

// pack 2 floats -> 2 fp16 (RTZ) as one u32
__device__ __forceinline__ unsigned pk2(float a, float b) {
    auto v = __builtin_amdgcn_cvt_pkrtz(a, b);
    return __builtin_bit_cast(unsigned, v);
}

// load 8 consecutive fp32 -> 8 fp16 (RNE) fragment
__device__ __forceinline__ f16x8 loadrow8(const float* p) {
    float4 lo = *reinterpret_cast<const float4*>(p);
    float4 hi = *reinterpret_cast<const float4*>(p + 4);
    f16x8 r;
    r[0] = (_Float16)lo.x; r[1] = (_Float16)lo.y;
    r[2] = (_Float16)lo.z; r[3] = (_Float16)lo.w;
    r[4] = (_Float16)hi.x; r[5] = (_Float16)hi.y;
    r[6] = (_Float16)hi.z; r[7] = (_Float16)hi.w;
    return r;
}

// LDS-only barrier (no vmcnt drain -> x prefetch stays in flight)
__device__ __forceinline__ void sync_lds() {
    asm volatile("s_waitcnt lgkmcnt(0)" ::: "memory");
    __builtin_amdgcn_s_barrier();
    asm volatile("" ::: "memory");
}

// Pin an f16x8 into VGPRs (opaque origin -> no remat/reload in the loop)
#define PIN8(f) do { uint4 _u = __builtin_bit_cast(uint4, (f));              \
    asm volatile("" : "+v"(_u.x), "+v"(_u.y), "+v"(_u.z), "+v"(_u.w));       \
    (f) = __builtin_bit_cast(f16x8, _u); } while (0)

// 12 waves per block = 4 independent batch-tiles x 3 layer-waves.
// wid = tile*3 + lay with round-robin wave->SIMD (wid%4): every SIMD gets
// exactly {one L0, one L1, one L2} from DIFFERENT tiles -> 3 independent
// waves per SIMD hide each other's dependency stalls.
// __launch_bounds__(768, 3): min 3 waves/EU => 1 workgroup/CU, VGPR cap
// 170 -- prevents the R16 failure where the backend targeted 2 wg/CU,
// capped VGPRs at 85, and spilled the pinned weights to scratch.
// Per-tile structure identical to R14/R15: 2 steps per barrier interval,
// deep-skew handoffs (consume data written 2 intervals ago, pre-read at
// top of interval), self-recurrent h in registers, fused-rcp activations.
// MFMA layout (verified R6): lane l, tile m holds i,f,g,o of unit
// 8*(l>>4)+m for batch l&15; lane's 8 h results ARE its next B-fragment.
__global__ __launch_bounds__(768, 3)
void lstm3_ws12_kernel(const float* __restrict__ x,
                       const float* __restrict__ Wih0, const float* __restrict__ Whh0,
                       const float* __restrict__ bih0, const float* __restrict__ bhh0,
                       const float* __restrict__ Wih1, const float* __restrict__ Whh1,
                       const float* __restrict__ bih1, const float* __restrict__ bhh1,
                       const float* __restrict__ Wih2, const float* __restrict__ Whh2,
                       const float* __restrict__ bih2, const float* __restrict__ bhh2,
                       const float* __restrict__ Wfc,  const float* __restrict__ bfc,
                       float* __restrict__ out)
{
    const int tid  = threadIdx.x;
    const int wid  = tid >> 6;        // 0..11
    const int lay  = wid % 3;         // layer 0..2   (wid = tile*3 + lay)
    const int tile = wid / 3;         // batch-tile 0..3
    const int l    = tid & 63;
    const int g    = l >> 4;          // lane group (k-chunk / C row-group)
    const int b    = l & 15;          // batch column
    const int qa   = l & 3;           // gate index for A-row loads
    const int gp   = (l & 15) >> 2;   // unit group for A-row loads
    const int b0   = (blockIdx.x * TILES + tile) * 16;

    __shared__ __align__(16) f16x8 hF0[TILES][3][2][64];   // h0 handoff
    __shared__ __align__(16) f16x8 hF1[TILES][3][2][64];   // h1 handoff

    // ---- weight fragments -> registers (pinned) ----
    f16x8 Fi[8], Fh[8];
    {
        const int rowA = qa * 32 + 8 * gp;
        const float* Pi = (lay == 1) ? Wih1 : ((lay == 2) ? Wih2 : nullptr);
        const float* Ph = (lay == 0) ? Whh0 : ((lay == 1) ? Whh1 : Whh2);
#pragma unroll
        for (int m = 0; m < 8; ++m) {
            Fh[m] = loadrow8(Ph + (rowA + m) * 32 + 8 * g);
            PIN8(Fh[m]);
        }
        if (lay != 0) {
#pragma unroll
            for (int m = 0; m < 8; ++m) {
                Fi[m] = loadrow8(Pi + (rowA + m) * 32 + 8 * g);
                PIN8(Fi[m]);
            }
        }
    }

    // ---- biases / Wih0 / Wfc -> registers (pre-scaled by +/-log2e) ----
    float4 bs[8], w0s[8];
    float wfc_r[8];
    {
        const float* BI = (lay == 0) ? bih0 : ((lay == 1) ? bih1 : bih2);
        const float* BH = (lay == 0) ? bhh0 : ((lay == 1) ? bhh1 : bhh2);
#pragma unroll
        for (int m = 0; m < 8; ++m) {
            const int u = 8 * g + m;
            const float bx = BI[u]      + BH[u];
            const float by = BI[u + 32] + BH[u + 32];
            const float bz = BI[u + 64] + BH[u + 64];
            const float bw = BI[u + 96] + BH[u + 96];
            bs[m] = make_float4(-L2E * bx, -L2E * by, 2.f * L2E * bz, -L2E * bw);
            if (lay == 0)
                w0s[m] = make_float4(-L2E * Wih0[u],          -L2E * Wih0[u + 32],
                                     2.f * L2E * Wih0[u + 64], -L2E * Wih0[u + 96]);
            if (lay == 2) wfc_r[m] = Wfc[u];
        }
    }
    const float bfc0 = bfc[0];

    {
        f16x8 zz = {0, 0, 0, 0, 0, 0, 0, 0};
        if (lay == 0) {
            hF0[tile][0][0][l] = zz; hF0[tile][0][1][l] = zz;
            hF0[tile][1][0][l] = zz; hF0[tile][1][1][l] = zz;
            hF0[tile][2][0][l] = zz; hF0[tile][2][1][l] = zz;
        } else if (lay == 1) {
            hF1[tile][0][0][l] = zz; hF1[tile][0][1][l] = zz;
            hF1[tile][1][0][l] = zz; hF1[tile][1][1][l] = zz;
            hF1[tile][2][0][l] = zz; hF1[tile][2][1][l] = zz;
        }
    }
    __syncthreads();

    float cst[8];
#pragma unroll
    for (int m = 0; m < 8; ++m) cst[m] = 0.f;
    f16x8 hself = {0, 0, 0, 0, 0, 0, 0, 0};   // own layer's h (register)
    f16x8 curA = hself, curB = hself;         // consumed handoff (2-iv-old)
    f16x8 nxtA = hself, nxtB = hself;

    float xvA = 0.f, xvB = 0.f;
    if (lay == 0) { xvA = x[b0 + b]; xvB = x[NBATCH + b0 + b]; }

    // fused-rcp LSTM step: acc[8] -> cst/hself (+fcv for lay2)
#define ACT_STEP(USE_X, XV)                                                  \
    do {                                                                     \
        float hn[8];                                                         \
        _Pragma("unroll")                                                    \
        for (int m = 0; m < 8; ++m) {                                        \
            float ti = fmaf(-L2E,      acc[m][0], bs[m].x);                  \
            float tf = fmaf(-L2E,      acc[m][1], bs[m].y);                  \
            float tg = fmaf(2.f * L2E, acc[m][2], bs[m].z);                  \
            float to = fmaf(-L2E,      acc[m][3], bs[m].w);                  \
            if (USE_X) {                                                     \
                ti = fmaf(w0s[m].x, (XV), ti);                               \
                tf = fmaf(w0s[m].y, (XV), tf);                               \
                tg = fmaf(w0s[m].z, (XV), tg);                               \
                to = fmaf(w0s[m].w, (XV), to);                               \
            }                                                                \
            const float ei = __builtin_amdgcn_exp2f(ti);                     \
            const float ef = __builtin_amdgcn_exp2f(tf);                     \
            const float eg = __builtin_amdgcn_exp2f(tg);                     \
            const float eo = __builtin_amdgcn_exp2f(to);                     \
            const float ig = (eg - 1.f) *                                    \
                __builtin_amdgcn_rcpf((1.f + ei) * (1.f + eg));              \
            const float ff = __builtin_amdgcn_rcpf(1.f + ef);                \
            cst[m] = fmaf(ff, cst[m], ig);                                   \
            const float tc = fminf(2.f * L2E * cst[m], 60.f);                \
            const float ec = __builtin_amdgcn_exp2f(tc);                     \
            hn[m] = (ec - 1.f) *                                             \
                __builtin_amdgcn_rcpf((1.f + eo) * (1.f + ec));              \
        }                                                                    \
        uint4 pk;                                                            \
        pk.x = pk2(hn[0], hn[1]); pk.y = pk2(hn[2], hn[3]);                  \
        pk.z = pk2(hn[4], hn[5]); pk.w = pk2(hn[6], hn[7]);                  \
        hself = __builtin_bit_cast(f16x8, pk);                               \
        fcv = 0.f;                                                           \
        if (lay == 2) {                                                      \
            _Pragma("unroll")                                                \
            for (int m = 0; m < 8; ++m) fcv = fmaf(wfc_r[m], hn[m], fcv);    \
        }                                                                    \
    } while (0)

    const int NIT = T_STEPS / 2 + 4;     // 1028
    int sw = 0, sp = 2;                  // write slot n%3; pre-read slot (n-1)%3
    for (int n = 0; n < NIT; ++n) {
        f32x4 acc[8];
        float fcv;
        if (lay == 0) {
            // ========== L0: t=2n, 2n+1 (self-chain fully in-register) =====
            if (n < T_STEPS / 2) {
                const int tp = 2 * n + 2;
                const int tA = (tp     < T_STEPS) ? tp     : T_STEPS - 1;
                const int tB = (tp + 1 < T_STEPS) ? tp + 1 : T_STEPS - 1;
                const float xnA = x[tA * NBATCH + b0 + b];   // prefetch
                const float xnB = x[tB * NBATCH + b0 + b];
#pragma unroll
                for (int m = 0; m < 8; ++m) {
                    f32x4 z = {0.f, 0.f, 0.f, 0.f};
                    acc[m] = __builtin_amdgcn_mfma_f32_16x16x32_f16(Fh[m], hself, z, 0, 0, 0);
                }
                ACT_STEP(1, xvA);
                hF0[tile][sw][0][l] = hself;
#pragma unroll
                for (int m = 0; m < 8; ++m) {
                    f32x4 z = {0.f, 0.f, 0.f, 0.f};
                    acc[m] = __builtin_amdgcn_mfma_f32_16x16x32_f16(Fh[m], hself, z, 0, 0, 0);
                }
                ACT_STEP(1, xvB);
                hF0[tile][sw][1][l] = hself;
                xvA = xnA; xvB = xnB;
            }
        } else if (lay == 1) {
            // ===== L1: t=2n-4, 2n-3 (consumes hF0 written at n-2, in regs) =
            nxtA = hF0[tile][sp][0][l];      // pre-read for interval n+1
            nxtB = hF0[tile][sp][1][l];
            if (n >= 2 && n <= T_STEPS / 2 + 1) {
#pragma unroll
                for (int m = 0; m < 8; ++m) {
                    f32x4 z = {0.f, 0.f, 0.f, 0.f};
                    z      = __builtin_amdgcn_mfma_f32_16x16x32_f16(Fi[m], curA, z, 0, 0, 0);
                    acc[m] = __builtin_amdgcn_mfma_f32_16x16x32_f16(Fh[m], hself, z, 0, 0, 0);
                }
                ACT_STEP(0, 0.f);
                hF1[tile][sw][0][l] = hself;
#pragma unroll
                for (int m = 0; m < 8; ++m) {
                    f32x4 z = {0.f, 0.f, 0.f, 0.f};
                    z      = __builtin_amdgcn_mfma_f32_16x16x32_f16(Fi[m], curB, z, 0, 0, 0);
                    acc[m] = __builtin_amdgcn_mfma_f32_16x16x32_f16(Fh[m], hself, z, 0, 0, 0);
                }
                ACT_STEP(0, 0.f);
                hF1[tile][sw][1][l] = hself;
            }
        } else {
            // ==== L2: t=2n-8, 2n-7 (consumes hF1 written at n-2) + FC =====
            nxtA = hF1[tile][sp][0][l];      // pre-read for interval n+1
            nxtB = hF1[tile][sp][1][l];
            if (n >= 4 && n <= T_STEPS / 2 + 3) {
#pragma unroll
                for (int m = 0; m < 8; ++m) {
                    f32x4 z = {0.f, 0.f, 0.f, 0.f};
                    z      = __builtin_amdgcn_mfma_f32_16x16x32_f16(Fi[m], curA, z, 0, 0, 0);
                    acc[m] = __builtin_amdgcn_mfma_f32_16x16x32_f16(Fh[m], hself, z, 0, 0, 0);
                }
                ACT_STEP(0, 0.f);
                {
                    float v = fcv;
                    v += __shfl_xor(v, 16);
                    v += __shfl_xor(v, 32);
                    if (l < 16) out[(2 * n - 8) * NBATCH + b0 + l] = v + bfc0;
                }
#pragma unroll
                for (int m = 0; m < 8; ++m) {
                    f32x4 z = {0.f, 0.f, 0.f, 0.f};
                    z      = __builtin_amdgcn_mfma_f32_16x16x32_f16(Fi[m], curB, z, 0, 0, 0);
                    acc[m] = __builtin_amdgcn_mfma_f32_16x16x32_f16(Fh[m], hself, z, 0, 0, 0);
                }
                ACT_STEP(0, 0.f);
                {
                    float v = fcv;
                    v += __shfl_xor(v, 16);
                    v += __shfl_xor(v, 32);
                    if (l < 16) out[(2 * n - 7) * NBATCH + b0 + l] = v + bfc0;
                }
            }
        }

        sync_lds();                   // pre-reads complete; slot lifetimes:
                                      // write n, pre-read n+1, rewrite n+3
        curA = nxtA; curB = nxtB;
        sp = sw; sw = (sw == 2) ? 0 : sw + 1;
    }
#undef ACT_STEP
}

extern "C" void kernel_launch(void* const* d_in, const int* in_sizes, int n_in,
                              void* d_out, int out_size, void* d_ws, size_t ws_size,
                              hipStream_t stream)
{
    const float* x    = (const float*)d_in[0];
    const float* Wih0 = (const float*)d_in[1];
    const float* Whh0 = (const float*)d_in[2];
    const float* bih0 = (const float*)d_in[3];
    const float* bhh0 = (const float*)d_in[4];
    const float* Wih1 = (const float*)d_in[5];
    const float* Whh1 = (const float*)d_in[6];
    const float* bih1 = (const float*)d_in[7];
    const float* bhh1 = (const float*)d_in[8];
    const float* Wih2 = (const float*)d_in[9];
    const float* Whh2 = (const float*)d_in[10];
    const float* bih2 = (const float*)d_in[11];
    const float* bhh2 = (const float*)d_in[12];
    const float* Wfc  = (const float*)d_in[13];
    const float* bfc  = (const float*)d_in[14];
    float* out        = (float*)d_out;

    lstm3_ws12_kernel<<<dim3(NBATCH / (16 * TILES)), dim3(64 * 3 * TILES), 0, stream>>>(
        x, Wih0, Whh0, bih0, bhh0,
        Wih1, Whh1, bih1, bhh1,
        Wih2, Whh2, bih2, bhh2,
        Wfc, bfc, out);
}

// Round 18
// 10726.216 us; speedup vs baseline: 1.0010x; 1.0010x over previous
//
#include <hip/hip_runtime.h>

#define T_STEPS 2048
#define NBATCH  1024
#define L2E     1.442695040888963f
#define TILES   4                     // batch-tiles per block

typedef _Float16 f16x8 __attribute__((ext_vector_type(8)));
typedef float    f32x4 __attribute__((ext_vector_type(4)));

// pack 2 floats -> 2 fp16 (RTZ) as one u32
__device__ __forceinline__ unsigned pk2(float a, float b) {
    auto v = __builtin_amdgcn_cvt_pkrtz(a, b);
    return __builtin_bit_cast(unsigned, v);
}

// load 8 consecutive fp32 -> 8 fp16 (RNE) fragment
__device__ __forceinline__ f16x8 loadrow8(const float* p) {
    float4 lo = *reinterpret_cast<const float4*>(p);
    float4 hi = *reinterpret_cast<const float4*>(p + 4);
    f16x8 r;
    r[0] = (_Float16)lo.x; r[1] = (_Float16)lo.y;
    r[2] = (_Float16)lo.z; r[3] = (_Float16)lo.w;
    r[4] = (_Float16)hi.x; r[5] = (_Float16)hi.y;
    r[6] = (_Float16)hi.z; r[7] = (_Float16)hi.w;
    return r;
}

// LDS-only barrier (no vmcnt drain -> x prefetch stays in flight)
__device__ __forceinline__ void sync_lds() {
    asm volatile("s_waitcnt lgkmcnt(0)" ::: "memory");
    __builtin_amdgcn_s_barrier();
    asm volatile("" ::: "memory");
}

// Pin an f16x8 into VGPRs (opaque origin -> no remat/reload in the loop)
#define PIN8(f) do { uint4 _u = __builtin_bit_cast(uint4, (f));              \
    asm volatile("" : "+v"(_u.x), "+v"(_u.y), "+v"(_u.z), "+v"(_u.w));       \
    (f) = __builtin_bit_cast(f16x8, _u); } while (0)

// 12 waves per block = 4 independent batch-tiles x 3 layer-waves.
// wid = tile*3 + lay with round-robin wave->SIMD (wid%4): every SIMD gets
// exactly {one L0, one L1, one L2} from DIFFERENT tiles -> 3 independent
// waves per SIMD hide each other's dependency stalls.
// amdgpu_waves_per_eu(3,3): pins the register allocator's occupancy TARGET
// at 3 waves/EU (VGPR budget 170). R16/R17's failure: __launch_bounds__'s
// 2nd arg only CAPS VGPRs; the allocator still targeted 6 waves/EU
// (2 blocks/CU by LDS), capped VGPRs at 85, and spilled pinned weights.
// Per-tile structure identical to R14/R15: 2 steps per barrier interval,
// deep-skew handoffs (consume data written 2 intervals ago, pre-read at
// top of interval), self-recurrent h in registers, fused-rcp activations.
// MFMA layout (verified R6): lane l, tile m holds i,f,g,o of unit
// 8*(l>>4)+m for batch l&15; lane's 8 h results ARE its next B-fragment.
__global__
__attribute__((amdgpu_flat_work_group_size(768, 768), amdgpu_waves_per_eu(3, 3)))
void lstm3_ws12_kernel(const float* __restrict__ x,
                       const float* __restrict__ Wih0, const float* __restrict__ Whh0,
                       const float* __restrict__ bih0, const float* __restrict__ bhh0,
                       const float* __restrict__ Wih1, const float* __restrict__ Whh1,
                       const float* __restrict__ bih1, const float* __restrict__ bhh1,
                       const float* __restrict__ Wih2, const float* __restrict__ Whh2,
                       const float* __restrict__ bih2, const float* __restrict__ bhh2,
                       const float* __restrict__ Wfc,  const float* __restrict__ bfc,
                       float* __restrict__ out)
{
    const int tid  = threadIdx.x;
    const int wid  = tid >> 6;        // 0..11
    const int lay  = wid % 3;         // layer 0..2   (wid = tile*3 + lay)
    const int tile = wid / 3;         // batch-tile 0..3
    const int l    = tid & 63;
    const int g    = l >> 4;          // lane group (k-chunk / C row-group)
    const int b    = l & 15;          // batch column
    const int qa   = l & 3;           // gate index for A-row loads
    const int gp   = (l & 15) >> 2;   // unit group for A-row loads
    const int b0   = (blockIdx.x * TILES + tile) * 16;

    __shared__ __align__(16) f16x8 hF0[TILES][3][2][64];   // h0 handoff
    __shared__ __align__(16) f16x8 hF1[TILES][3][2][64];   // h1 handoff

    // ---- weight fragments -> registers (pinned) ----
    f16x8 Fi[8], Fh[8];
    {
        const int rowA = qa * 32 + 8 * gp;
        const float* Pi = (lay == 1) ? Wih1 : ((lay == 2) ? Wih2 : nullptr);
        const float* Ph = (lay == 0) ? Whh0 : ((lay == 1) ? Whh1 : Whh2);
#pragma unroll
        for (int m = 0; m < 8; ++m) {
            Fh[m] = loadrow8(Ph + (rowA + m) * 32 + 8 * g);
            PIN8(Fh[m]);
        }
        if (lay != 0) {
#pragma unroll
            for (int m = 0; m < 8; ++m) {
                Fi[m] = loadrow8(Pi + (rowA + m) * 32 + 8 * g);
                PIN8(Fi[m]);
            }
        }
    }

    // ---- biases / Wih0 / Wfc -> registers (pre-scaled by +/-log2e) ----
    float4 bs[8], w0s[8];
    float wfc_r[8];
    {
        const float* BI = (lay == 0) ? bih0 : ((lay == 1) ? bih1 : bih2);
        const float* BH = (lay == 0) ? bhh0 : ((lay == 1) ? bhh1 : bhh2);
#pragma unroll
        for (int m = 0; m < 8; ++m) {
            const int u = 8 * g + m;
            const float bx = BI[u]      + BH[u];
            const float by = BI[u + 32] + BH[u + 32];
            const float bz = BI[u + 64] + BH[u + 64];
            const float bw = BI[u + 96] + BH[u + 96];
            bs[m] = make_float4(-L2E * bx, -L2E * by, 2.f * L2E * bz, -L2E * bw);
            if (lay == 0)
                w0s[m] = make_float4(-L2E * Wih0[u],          -L2E * Wih0[u + 32],
                                     2.f * L2E * Wih0[u + 64], -L2E * Wih0[u + 96]);
            if (lay == 2) wfc_r[m] = Wfc[u];
        }
    }
    const float bfc0 = bfc[0];

    {
        f16x8 zz = {0, 0, 0, 0, 0, 0, 0, 0};
        if (lay == 0) {
            hF0[tile][0][0][l] = zz; hF0[tile][0][1][l] = zz;
            hF0[tile][1][0][l] = zz; hF0[tile][1][1][l] = zz;
            hF0[tile][2][0][l] = zz; hF0[tile][2][1][l] = zz;
        } else if (lay == 1) {
            hF1[tile][0][0][l] = zz; hF1[tile][0][1][l] = zz;
            hF1[tile][1][0][l] = zz; hF1[tile][1][1][l] = zz;
            hF1[tile][2][0][l] = zz; hF1[tile][2][1][l] = zz;
        }
    }
    __syncthreads();

    float cst[8];
#pragma unroll
    for (int m = 0; m < 8; ++m) cst[m] = 0.f;
    f16x8 hself = {0, 0, 0, 0, 0, 0, 0, 0};   // own layer's h (register)
    f16x8 curA = hself, curB = hself;         // consumed handoff (2-iv-old)
    f16x8 nxtA = hself, nxtB = hself;

    float xvA = 0.f, xvB = 0.f;
    if (lay == 0) { xvA = x[b0 + b]; xvB = x[NBATCH + b0 + b]; }

    // fused-rcp LSTM step: acc[8] -> cst/hself (+fcv for lay2)
#define ACT_STEP(USE_X, XV)                                                  \
    do {                                                                     \
        float hn[8];                                                         \
        _Pragma("unroll")                                                    \
        for (int m = 0; m < 8; ++m) {                                        \
            float ti = fmaf(-L2E,      acc[m][0], bs[m].x);                  \
            float tf = fmaf(-L2E,      acc[m][1], bs[m].y);                  \
            float tg = fmaf(2.f * L2E, acc[m][2], bs[m].z);                  \
            float to = fmaf(-L2E,      acc[m][3], bs[m].w);                  \
            if (USE_X) {                                                     \
                ti = fmaf(w0s[m].x, (XV), ti);                               \
                tf = fmaf(w0s[m].y, (XV), tf);                               \
                tg = fmaf(w0s[m].z, (XV), tg);                               \
                to = fmaf(w0s[m].w, (XV), to);                               \
            }                                                                \
            const float ei = __builtin_amdgcn_exp2f(ti);                     \
            const float ef = __builtin_amdgcn_exp2f(tf);                     \
            const float eg = __builtin_amdgcn_exp2f(tg);                     \
            const float eo = __builtin_amdgcn_exp2f(to);                     \
            const float ig = (eg - 1.f) *                                    \
                __builtin_amdgcn_rcpf((1.f + ei) * (1.f + eg));              \
            const float ff = __builtin_amdgcn_rcpf(1.f + ef);                \
            cst[m] = fmaf(ff, cst[m], ig);                                   \
            const float tc = fminf(2.f * L2E * cst[m], 60.f);                \
            const float ec = __builtin_amdgcn_exp2f(tc);                     \
            hn[m] = (ec - 1.f) *                                             \
                __builtin_amdgcn_rcpf((1.f + eo) * (1.f + ec));              \
        }                                                                    \
        uint4 pk;                                                            \
        pk.x = pk2(hn[0], hn[1]); pk.y = pk2(hn[2], hn[3]);                  \
        pk.z = pk2(hn[4], hn[5]); pk.w = pk2(hn[6], hn[7]);                  \
        hself = __builtin_bit_cast(f16x8, pk);                               \
        fcv = 0.f;                                                           \
        if (lay == 2) {                                                      \
            _Pragma("unroll")                                                \
            for (int m = 0; m < 8; ++m) fcv = fmaf(wfc_r[m], hn[m], fcv);    \
        }                                                                    \
    } while (0)

    const int NIT = T_STEPS / 2 + 4;     // 1028
    int sw = 0, sp = 2;                  // write slot n%3; pre-read slot (n-1)%3
    for (int n = 0; n < NIT; ++n) {
        f32x4 acc[8];
        float fcv;
        if (lay == 0) {
            // ========== L0: t=2n, 2n+1 (self-chain fully in-register) =====
            if (n < T_STEPS / 2) {
                const int tp = 2 * n + 2;
                const int tA = (tp     < T_STEPS) ? tp     : T_STEPS - 1;
                const int tB = (tp + 1 < T_STEPS) ? tp + 1 : T_STEPS - 1;
                const float xnA = x[tA * NBATCH + b0 + b];   // prefetch
                const float xnB = x[tB * NBATCH + b0 + b];
#pragma unroll
                for (int m = 0; m < 8; ++m) {
                    f32x4 z = {0.f, 0.f, 0.f, 0.f};
                    acc[m] = __builtin_amdgcn_mfma_f32_16x16x32_f16(Fh[m], hself, z, 0, 0, 0);
                }
                ACT_STEP(1, xvA);
                hF0[tile][sw][0][l] = hself;
#pragma unroll
                for (int m = 0; m < 8; ++m) {
                    f32x4 z = {0.f, 0.f, 0.f, 0.f};
                    acc[m] = __builtin_amdgcn_mfma_f32_16x16x32_f16(Fh[m], hself, z, 0, 0, 0);
                }
                ACT_STEP(1, xvB);
                hF0[tile][sw][1][l] = hself;
                xvA = xnA; xvB = xnB;
            }
        } else if (lay == 1) {
            // ===== L1: t=2n-4, 2n-3 (consumes hF0 written at n-2, in regs) =
            nxtA = hF0[tile][sp][0][l];      // pre-read for interval n+1
            nxtB = hF0[tile][sp][1][l];
            if (n >= 2 && n <= T_STEPS / 2 + 1) {
#pragma unroll
                for (int m = 0; m < 8; ++m) {
                    f32x4 z = {0.f, 0.f, 0.f, 0.f};
                    z      = __builtin_amdgcn_mfma_f32_16x16x32_f16(Fi[m], curA, z, 0, 0, 0);
                    acc[m] = __builtin_amdgcn_mfma_f32_16x16x32_f16(Fh[m], hself, z, 0, 0, 0);
                }
                ACT_STEP(0, 0.f);
                hF1[tile][sw][0][l] = hself;
#pragma unroll
                for (int m = 0; m < 8; ++m) {
                    f32x4 z = {0.f, 0.f, 0.f, 0.f};
                    z      = __builtin_amdgcn_mfma_f32_16x16x32_f16(Fi[m], curB, z, 0, 0, 0);
                    acc[m] = __builtin_amdgcn_mfma_f32_16x16x32_f16(Fh[m], hself, z, 0, 0, 0);
                }
                ACT_STEP(0, 0.f);
                hF1[tile][sw][1][l] = hself;
            }
        } else {
            // ==== L2: t=2n-8, 2n-7 (consumes hF1 written at n-2) + FC =====
            nxtA = hF1[tile][sp][0][l];      // pre-read for interval n+1
            nxtB = hF1[tile][sp][1][l];
            if (n >= 4 && n <= T_STEPS / 2 + 3) {
#pragma unroll
                for (int m = 0; m < 8; ++m) {
                    f32x4 z = {0.f, 0.f, 0.f, 0.f};
                    z      = __builtin_amdgcn_mfma_f32_16x16x32_f16(Fi[m], curA, z, 0, 0, 0);
                    acc[m] = __builtin_amdgcn_mfma_f32_16x16x32_f16(Fh[m], hself, z, 0, 0, 0);
                }
                ACT_STEP(0, 0.f);
                {
                    float v = fcv;
                    v += __shfl_xor(v, 16);
                    v += __shfl_xor(v, 32);
                    if (l < 16) out[(2 * n - 8) * NBATCH + b0 + l] = v + bfc0;
                }
#pragma unroll
                for (int m = 0; m < 8; ++m) {
                    f32x4 z = {0.f, 0.f, 0.f, 0.f};
                    z      = __builtin_amdgcn_mfma_f32_16x16x32_f16(Fi[m], curB, z, 0, 0, 0);
                    acc[m] = __builtin_amdgcn_mfma_f32_16x16x32_f16(Fh[m], hself, z, 0, 0, 0);
                }
                ACT_STEP(0, 0.f);
                {
                    float v = fcv;
                    v += __shfl_xor(v, 16);
                    v += __shfl_xor(v, 32);
                    if (l < 16) out[(2 * n - 7) * NBATCH + b0 + l] = v + bfc0;
                }
            }
        }

        sync_lds();                   // pre-reads complete; slot lifetimes:
                                      // write n, pre-read n+1, rewrite n+3
        curA = nxtA; curB = nxtB;
        sp = sw; sw = (sw == 2) ? 0 : sw + 1;
    }
#undef ACT_STEP
}

extern "C" void kernel_launch(void* const* d_in, const int* in_sizes, int n_in,
                              void* d_out, int out_size, void* d_ws, size_t ws_size,
                              hipStream_t stream)
{
    const float* x    = (const float*)d_in[0];
    const float* Wih0 = (const float*)d_in[1];
    const float* Whh0 = (const float*)d_in[2];
    const float* bih0 = (const float*)d_in[3];
    const float* bhh0 = (const float*)d_in[4];
    const float* Wih1 = (const float*)d_in[5];
    const float* Whh1 = (const float*)d_in[6];
    const float* bih1 = (const float*)d_in[7];
    const float* bhh1 = (const float*)d_in[8];
    const float* Wih2 = (const float*)d_in[9];
    const float* Whh2 = (const float*)d_in[10];
    const float* bih2 = (const float*)d_in[11];
    const float* bhh2 = (const float*)d_in[12];
    const float* Wfc  = (const float*)d_in[13];
    const float* bfc  = (const float*)d_in[14];
    float* out        = (float*)d_out;

    lstm3_ws12_kernel<<<dim3(NBATCH / (16 * TILES)), dim3(64 * 3 * TILES), 0, stream>>>(
        x, Wih0, Whh0, bih0, bhh0,
        Wih1, Whh1, bih1, bhh1,
        Wih2, Whh2, bih2, bhh2,
        Wfc, bfc, out);
}

// Round 19
// 1535.100 us; speedup vs baseline: 6.9940x; 6.9873x over previous
//
#include <hip/hip_runtime.h>

#define T_STEPS 2048
#define NBATCH  1024
#define L2E     1.442695040888963f

typedef _Float16 f16x8 __attribute__((ext_vector_type(8)));
typedef float    f32x4 __attribute__((ext_vector_type(4)));

// pack 2 floats -> 2 fp16 (RTZ) as one u32
__device__ __forceinline__ unsigned pk2(float a, float b) {
    auto v = __builtin_amdgcn_cvt_pkrtz(a, b);
    return __builtin_bit_cast(unsigned, v);
}

// load 8 consecutive fp32 -> 8 fp16 (RNE) fragment
__device__ __forceinline__ f16x8 loadrow8(const float* p) {
    float4 lo = *reinterpret_cast<const float4*>(p);
    float4 hi = *reinterpret_cast<const float4*>(p + 4);
    f16x8 r;
    r[0] = (_Float16)lo.x; r[1] = (_Float16)lo.y;
    r[2] = (_Float16)lo.z; r[3] = (_Float16)lo.w;
    r[4] = (_Float16)hi.x; r[5] = (_Float16)hi.y;
    r[6] = (_Float16)hi.z; r[7] = (_Float16)hi.w;
    return r;
}

// LDS-only barrier (no vmcnt drain -> x prefetch stays in flight)
__device__ __forceinline__ void sync_lds() {
    asm volatile("s_waitcnt lgkmcnt(0)" ::: "memory");
    __builtin_amdgcn_s_barrier();
    asm volatile("" ::: "memory");
}

// Pin an f16x8 into VGPRs (opaque origin -> no remat/reload in the loop)
#define PIN8(f) do { uint4 _u = __builtin_bit_cast(uint4, (f));              \
    asm volatile("" : "+v"(_u.x), "+v"(_u.y), "+v"(_u.z), "+v"(_u.w));       \
    (f) = __builtin_bit_cast(f16x8, _u); } while (0)

// 6 waves per block = 3 layers x 2 m-halves; 16 batch columns per block;
// 64 blocks -> 384 SIMDs busy (2x the 3-wave layout's 192).
// Each wave owns m-tiles {half*4..half*4+3}: 4 MFMA A-frags (+4 for Wih),
// ~90 VGPRs total -- under the allocator's no-spill line for 384-thread
// blocks (R5/R11 evidence: allocator grants need; 768-thread blocks cap
// at 84 and spill -- R16/R18 failure mode).
// ONE step per interval. ALL h vectors live in 3-slot rotating LDS:
// written at interval n (own half, 8B), read-at-top at n+1 (full 16B),
// slot rewritten at n+3 -- one lgkm-only barrier per interval.
// Skew: L0 computes t=n, L1 t=n-1, L2 t=n-2; FC halves combine through
// FCpart with a 1-interval pipeline (half0 -> LDS, half1 adds & stores).
// MFMA layout (verified R6): lane l, tile m holds i,f,g,o of unit
// 8*(l>>4)+m for batch l&15; element e of lane's B-frag = h of unit
// 8*(l>>4)+e -> full frag = concat of the two halves' 8B packs.
__global__ __launch_bounds__(384, 1)
void lstm3_ws6h_kernel(const float* __restrict__ x,
                       const float* __restrict__ Wih0, const float* __restrict__ Whh0,
                       const float* __restrict__ bih0, const float* __restrict__ bhh0,
                       const float* __restrict__ Wih1, const float* __restrict__ Whh1,
                       const float* __restrict__ bih1, const float* __restrict__ bhh1,
                       const float* __restrict__ Wih2, const float* __restrict__ Whh2,
                       const float* __restrict__ bih2, const float* __restrict__ bhh2,
                       const float* __restrict__ Wfc,  const float* __restrict__ bfc,
                       float* __restrict__ out)
{
    const int tid  = threadIdx.x;
    const int wid  = tid >> 6;        // 0..5
    const int lay  = wid >> 1;        // layer 0..2
    const int half = wid & 1;         // m-half
    const int l    = tid & 63;
    const int g    = l >> 4;          // lane group (k-chunk / C row-group)
    const int b    = l & 15;          // batch column
    const int qa   = l & 3;           // gate index for A-row loads
    const int gp   = (l & 15) >> 2;   // unit group for A-row loads
    const int b0   = blockIdx.x * 16;
    const int m0   = half * 4;        // this wave's m-tile base

    __shared__ __align__(16) f16x8 hH[3][3][64];   // [slot][layer][lane]
    __shared__ float FCpart[3][16];

    // ---- weight fragments -> registers (pinned) ----
    f16x8 Fi[4], Fh[4];
    {
        const int rowA = qa * 32 + 8 * gp + m0;
        const float* Pi = (lay == 1) ? Wih1 : ((lay == 2) ? Wih2 : nullptr);
        const float* Ph = (lay == 0) ? Whh0 : ((lay == 1) ? Whh1 : Whh2);
#pragma unroll
        for (int mm = 0; mm < 4; ++mm) {
            Fh[mm] = loadrow8(Ph + (rowA + mm) * 32 + 8 * g);
            PIN8(Fh[mm]);
        }
        if (lay != 0) {
#pragma unroll
            for (int mm = 0; mm < 4; ++mm) {
                Fi[mm] = loadrow8(Pi + (rowA + mm) * 32 + 8 * g);
                PIN8(Fi[mm]);
            }
        }
    }

    // ---- biases / Wih0 / Wfc -> registers (pre-scaled by +/-log2e) ----
    float4 bs[4], w0s[4];
    float wfc_r[4];
    {
        const float* BI = (lay == 0) ? bih0 : ((lay == 1) ? bih1 : bih2);
        const float* BH = (lay == 0) ? bhh0 : ((lay == 1) ? bhh1 : bhh2);
#pragma unroll
        for (int mm = 0; mm < 4; ++mm) {
            const int u = 8 * g + m0 + mm;
            const float bx = BI[u]      + BH[u];
            const float by = BI[u + 32] + BH[u + 32];
            const float bz = BI[u + 64] + BH[u + 64];
            const float bw = BI[u + 96] + BH[u + 96];
            bs[mm] = make_float4(-L2E * bx, -L2E * by, 2.f * L2E * bz, -L2E * bw);
            if (lay == 0)
                w0s[mm] = make_float4(-L2E * Wih0[u],          -L2E * Wih0[u + 32],
                                      2.f * L2E * Wih0[u + 64], -L2E * Wih0[u + 96]);
            if (lay == 2) wfc_r[mm] = Wfc[u];
        }
    }
    const float bfc0 = bfc[0];

    if (half == 0) {                  // zero all slots of own layer
        f16x8 zz = {0, 0, 0, 0, 0, 0, 0, 0};
        hH[0][lay][l] = zz; hH[1][lay][l] = zz; hH[2][lay][l] = zz;
    }
    __syncthreads();

    float cst[4] = {0.f, 0.f, 0.f, 0.f};
    float vprev = 0.f;                // L2 half1: own FC partial, 1-iv delayed
    float xv = (lay == 0) ? x[b0 + b] : 0.f;

    // fused-rcp LSTM step on 4 units: acc[4] -> cst, hn[4]
#define ACT4(USE_X, XV)                                                      \
    do {                                                                     \
        _Pragma("unroll")                                                    \
        for (int mm = 0; mm < 4; ++mm) {                                     \
            float ti = fmaf(-L2E,      acc[mm][0], bs[mm].x);                \
            float tf = fmaf(-L2E,      acc[mm][1], bs[mm].y);                \
            float tg = fmaf(2.f * L2E, acc[mm][2], bs[mm].z);                \
            float to = fmaf(-L2E,      acc[mm][3], bs[mm].w);                \
            if (USE_X) {                                                     \
                ti = fmaf(w0s[mm].x, (XV), ti);                              \
                tf = fmaf(w0s[mm].y, (XV), tf);                              \
                tg = fmaf(w0s[mm].z, (XV), tg);                              \
                to = fmaf(w0s[mm].w, (XV), to);                              \
            }                                                                \
            const float ei = __builtin_amdgcn_exp2f(ti);                     \
            const float ef = __builtin_amdgcn_exp2f(tf);                     \
            const float eg = __builtin_amdgcn_exp2f(tg);                     \
            const float eo = __builtin_amdgcn_exp2f(to);                     \
            const float ig = (eg - 1.f) *                                    \
                __builtin_amdgcn_rcpf((1.f + ei) * (1.f + eg));              \
            const float ff = __builtin_amdgcn_rcpf(1.f + ef);                \
            cst[mm] = fmaf(ff, cst[mm], ig);                                 \
            const float tc = fminf(2.f * L2E * cst[mm], 60.f);               \
            const float ec = __builtin_amdgcn_exp2f(tc);                     \
            hn[mm] = (ec - 1.f) *                                            \
                __builtin_amdgcn_rcpf((1.f + eo) * (1.f + ec));              \
        }                                                                    \
    } while (0)

    const int NIT = T_STEPS + 3;      // 2051
    int sw = 0, sp = 2;               // write slot n%3, read slot (n-1)%3
    for (int n = 0; n < NIT; ++n) {
        f32x4 acc[4];
        float hn[4];
        if (lay == 0) {
            // ========== L0(t=n): gates = Whh0 @ h0(n-1) + Wih0*x + b ======
            if (n < T_STEPS) {
                const int tn = (n + 1 < T_STEPS) ? n + 1 : T_STEPS - 1;
                const float xn = x[tn * NBATCH + b0 + b];   // prefetch
                const f16x8 hb0 = hH[sp][0][l];
#pragma unroll
                for (int mm = 0; mm < 4; ++mm) {
                    f32x4 z = {0.f, 0.f, 0.f, 0.f};
                    acc[mm] = __builtin_amdgcn_mfma_f32_16x16x32_f16(Fh[mm], hb0, z, 0, 0, 0);
                }
                ACT4(1, xv);
                uint2 pk;
                pk.x = pk2(hn[0], hn[1]);
                pk.y = pk2(hn[2], hn[3]);
                *(reinterpret_cast<uint2*>(&hH[sw][0][l]) + half) = pk;
                xv = xn;
            }
        } else if (lay == 1) {
            // ====== L1(t=n-1): gates = Wih1 @ h0(n-1) + Whh1 @ h1(n-2) ====
            if (n >= 1 && n <= T_STEPS) {
                const f16x8 hb0 = hH[sp][0][l];
                const f16x8 hb1 = hH[sp][1][l];
#pragma unroll
                for (int mm = 0; mm < 4; ++mm) {
                    f32x4 z = {0.f, 0.f, 0.f, 0.f};
                    z       = __builtin_amdgcn_mfma_f32_16x16x32_f16(Fi[mm], hb0, z, 0, 0, 0);
                    acc[mm] = __builtin_amdgcn_mfma_f32_16x16x32_f16(Fh[mm], hb1, z, 0, 0, 0);
                }
                ACT4(0, 0.f);
                uint2 pk;
                pk.x = pk2(hn[0], hn[1]);
                pk.y = pk2(hn[2], hn[3]);
                *(reinterpret_cast<uint2*>(&hH[sw][1][l]) + half) = pk;
            }
        } else {
            // == L2(t=n-2): gates = Wih2 @ h1(n-2) + Whh2 @ h2(n-3); FC ====
            // half1 first: store out[t=n-3] from FCpart(n-1) + vprev(n-1)
            if (half == 1 && n >= 3 && l < 16)
                out[(n - 3) * NBATCH + b0 + l] = FCpart[sp][l] + vprev + bfc0;
            if (n >= 2 && n <= T_STEPS + 1) {
                const f16x8 hb1 = hH[sp][1][l];
                const f16x8 hb2 = hH[sp][2][l];
#pragma unroll
                for (int mm = 0; mm < 4; ++mm) {
                    f32x4 z = {0.f, 0.f, 0.f, 0.f};
                    z       = __builtin_amdgcn_mfma_f32_16x16x32_f16(Fi[mm], hb1, z, 0, 0, 0);
                    acc[mm] = __builtin_amdgcn_mfma_f32_16x16x32_f16(Fh[mm], hb2, z, 0, 0, 0);
                }
                ACT4(0, 0.f);
                uint2 pk;
                pk.x = pk2(hn[0], hn[1]);
                pk.y = pk2(hn[2], hn[3]);
                *(reinterpret_cast<uint2*>(&hH[sw][2][l]) + half) = pk;
                float v = 0.f;
#pragma unroll
                for (int mm = 0; mm < 4; ++mm) v = fmaf(wfc_r[mm], hn[mm], v);
                v += __shfl_xor(v, 16);
                v += __shfl_xor(v, 32);
                if (half == 0) { if (l < 16) FCpart[sw][l] = v; }
                else           { vprev = v; }
            }
        }

        sync_lds();                   // reads of slot sp complete (lgkmcnt);
                                      // slot sp is rewritten 2 barriers later
        sp = sw; sw = (sw == 2) ? 0 : sw + 1;
    }
#undef ACT4
}

extern "C" void kernel_launch(void* const* d_in, const int* in_sizes, int n_in,
                              void* d_out, int out_size, void* d_ws, size_t ws_size,
                              hipStream_t stream)
{
    const float* x    = (const float*)d_in[0];
    const float* Wih0 = (const float*)d_in[1];
    const float* Whh0 = (const float*)d_in[2];
    const float* bih0 = (const float*)d_in[3];
    const float* bhh0 = (const float*)d_in[4];
    const float* Wih1 = (const float*)d_in[5];
    const float* Whh1 = (const float*)d_in[6];
    const float* bih1 = (const float*)d_in[7];
    const float* bhh1 = (const float*)d_in[8];
    const float* Wih2 = (const float*)d_in[9];
    const float* Whh2 = (const float*)d_in[10];
    const float* bih2 = (const float*)d_in[11];
    const float* bhh2 = (const float*)d_in[12];
    const float* Wfc  = (const float*)d_in[13];
    const float* bfc  = (const float*)d_in[14];
    float* out        = (float*)d_out;

    lstm3_ws6h_kernel<<<dim3(NBATCH / 16), dim3(384), 0, stream>>>(
        x, Wih0, Whh0, bih0, bhh0,
        Wih1, Whh1, bih1, bhh1,
        Wih2, Whh2, bih2, bhh2,
        Wfc, bfc, out);
}

// Round 20
// 1248.630 us; speedup vs baseline: 8.5986x; 1.2294x over previous
//
#include <hip/hip_runtime.h>

#define T_STEPS 2048
#define NBATCH  1024
#define L2E     1.442695040888963f

typedef _Float16 f16x8 __attribute__((ext_vector_type(8)));
typedef float    f32x4 __attribute__((ext_vector_type(4)));

// pack 2 floats -> 2 fp16 (RTZ) as one u32
__device__ __forceinline__ unsigned pk2(float a, float b) {
    auto v = __builtin_amdgcn_cvt_pkrtz(a, b);
    return __builtin_bit_cast(unsigned, v);
}

// load 8 consecutive fp32 -> 8 fp16 (RNE) fragment
__device__ __forceinline__ f16x8 loadrow8(const float* p) {
    float4 lo = *reinterpret_cast<const float4*>(p);
    float4 hi = *reinterpret_cast<const float4*>(p + 4);
    f16x8 r;
    r[0] = (_Float16)lo.x; r[1] = (_Float16)lo.y;
    r[2] = (_Float16)lo.z; r[3] = (_Float16)lo.w;
    r[4] = (_Float16)hi.x; r[5] = (_Float16)hi.y;
    r[6] = (_Float16)hi.z; r[7] = (_Float16)hi.w;
    return r;
}

// LDS-only barrier (no vmcnt drain -> x prefetch stays in flight)
__device__ __forceinline__ void sync_lds() {
    asm volatile("s_waitcnt lgkmcnt(0)" ::: "memory");
    __builtin_amdgcn_s_barrier();
    asm volatile("" ::: "memory");
}

// Pin an f16x8 into VGPRs (opaque origin -> no remat/reload in the loop)
#define PIN8(f) do { uint4 _u = __builtin_bit_cast(uint4, (f));              \
    asm volatile("" : "+v"(_u.x), "+v"(_u.y), "+v"(_u.z), "+v"(_u.w));       \
    (f) = __builtin_bit_cast(f16x8, _u); } while (0)

// 12 waves per block = 3 layers x 4 m-quarters; 16 batch columns per block.
// wid = lay*4 + q  =>  SIMD (wid&3) = q hosts exactly {L0,L1,L2} -- perfectly
// balanced 3 waves/SIMD (R19's 6-wave layout put 2 waves on half the SIMDs;
// the barrier waited on those). Each wave owns m-tiles {2q, 2q+1}: 2-4 A-frags
// in registers (~70 VGPRs need). An 84KB LDS pad forces 1 block/CU so the
// register allocator targets 3 waves/EU (170 VGPR cap) -- avoiding the
// R16/R17/R18 heuristic (2 blocks/CU -> 85 cap -> spill of pinned weights).
// ONE step per interval; h through 3-slot rotating LDS (write n, read n+1,
// rewrite n+3); one lgkm-only barrier per interval. Skew: L0 t=n, L1 t=n-1,
// L2 t=n-2; FC: quarters 0-2 -> FCpart, quarter 3 sums + stores next interval.
// MFMA layout (verified R6): lane l, tile m holds i,f,g,o of unit 8*(l>>4)+m
// for batch l&15; element e of lane's B-frag = h of unit 8*(l>>4)+e -> each
// quarter contributes one dword (2 fp16) of the 16B lane slot.
__global__ __launch_bounds__(768, 1)
void lstm3_ws12q_kernel(const float* __restrict__ x,
                        const float* __restrict__ Wih0, const float* __restrict__ Whh0,
                        const float* __restrict__ bih0, const float* __restrict__ bhh0,
                        const float* __restrict__ Wih1, const float* __restrict__ Whh1,
                        const float* __restrict__ bih1, const float* __restrict__ bhh1,
                        const float* __restrict__ Wih2, const float* __restrict__ Whh2,
                        const float* __restrict__ bih2, const float* __restrict__ bhh2,
                        const float* __restrict__ Wfc,  const float* __restrict__ bfc,
                        float* __restrict__ out)
{
    const int tid = threadIdx.x;
    const int wid = tid >> 6;         // 0..11
    const int lay = wid >> 2;         // layer 0..2
    const int q   = wid & 3;          // m-quarter == SIMD id
    const int l   = tid & 63;
    const int g   = l >> 4;           // lane group (k-chunk / C row-group)
    const int b   = l & 15;           // batch column
    const int qa  = l & 3;            // gate index for A-row loads
    const int gp  = (l & 15) >> 2;    // unit group for A-row loads
    const int b0  = blockIdx.x * 16;
    const int m0  = q * 2;            // this wave's m-tile base

    __shared__ __align__(16) f16x8 hH[3][3][64];   // [slot][layer][lane]
    __shared__ float FCpart[3][3][16];             // [slot][quarter 0..2][col]
    __shared__ char  pad[86016];                   // forces 1 block/CU

    // ---- weight fragments -> registers (pinned) ----
    f16x8 Fi[2], Fh[2];
    {
        const int rowA = qa * 32 + 8 * gp + m0;
        const float* Pi = (lay == 1) ? Wih1 : ((lay == 2) ? Wih2 : nullptr);
        const float* Ph = (lay == 0) ? Whh0 : ((lay == 1) ? Whh1 : Whh2);
#pragma unroll
        for (int mm = 0; mm < 2; ++mm) {
            Fh[mm] = loadrow8(Ph + (rowA + mm) * 32 + 8 * g);
            PIN8(Fh[mm]);
        }
        if (lay != 0) {
#pragma unroll
            for (int mm = 0; mm < 2; ++mm) {
                Fi[mm] = loadrow8(Pi + (rowA + mm) * 32 + 8 * g);
                PIN8(Fi[mm]);
            }
        }
    }

    // ---- biases / Wih0 / Wfc -> registers (pre-scaled by +/-log2e) ----
    float4 bs[2], w0s[2];
    float wfc_r[2];
    {
        const float* BI = (lay == 0) ? bih0 : ((lay == 1) ? bih1 : bih2);
        const float* BH = (lay == 0) ? bhh0 : ((lay == 1) ? bhh1 : bhh2);
#pragma unroll
        for (int mm = 0; mm < 2; ++mm) {
            const int u = 8 * g + m0 + mm;
            const float bx = BI[u]      + BH[u];
            const float by = BI[u + 32] + BH[u + 32];
            const float bz = BI[u + 64] + BH[u + 64];
            const float bw = BI[u + 96] + BH[u + 96];
            bs[mm] = make_float4(-L2E * bx, -L2E * by, 2.f * L2E * bz, -L2E * bw);
            if (lay == 0)
                w0s[mm] = make_float4(-L2E * Wih0[u],          -L2E * Wih0[u + 32],
                                      2.f * L2E * Wih0[u + 64], -L2E * Wih0[u + 96]);
            if (lay == 2) wfc_r[mm] = Wfc[u];
        }
    }
    const float bfc0 = bfc[0];

    // keep pad alive (runtime-false; bfc0 is ~uniform(-s,s), never 1e30)
    if (bfc0 == 1e30f) { pad[tid] = 1; out[0] = pad[0]; }

    if (q == 0) {                     // zero all slots of own layer
        f16x8 zz = {0, 0, 0, 0, 0, 0, 0, 0};
        hH[0][lay][l] = zz; hH[1][lay][l] = zz; hH[2][lay][l] = zz;
    }
    if (lay == 2 && q == 0 && l < 16) {
        FCpart[0][0][l] = 0.f; FCpart[0][1][l] = 0.f; FCpart[0][2][l] = 0.f;
        FCpart[1][0][l] = 0.f; FCpart[1][1][l] = 0.f; FCpart[1][2][l] = 0.f;
        FCpart[2][0][l] = 0.f; FCpart[2][1][l] = 0.f; FCpart[2][2][l] = 0.f;
    }
    __syncthreads();

    float cst[2] = {0.f, 0.f};
    float vprev = 0.f;                // L2 q3: own FC partial, 1-iv delayed
    float xv = (lay == 0) ? x[b0 + b] : 0.f;

    // fused-rcp LSTM step on 2 m-tiles: acc[2] -> cst, hn[2]
#define ACT2(USE_X, XV)                                                      \
    do {                                                                     \
        _Pragma("unroll")                                                    \
        for (int mm = 0; mm < 2; ++mm) {                                     \
            float ti = fmaf(-L2E,      acc[mm][0], bs[mm].x);                \
            float tf = fmaf(-L2E,      acc[mm][1], bs[mm].y);                \
            float tg = fmaf(2.f * L2E, acc[mm][2], bs[mm].z);                \
            float to = fmaf(-L2E,      acc[mm][3], bs[mm].w);                \
            if (USE_X) {                                                     \
                ti = fmaf(w0s[mm].x, (XV), ti);                              \
                tf = fmaf(w0s[mm].y, (XV), tf);                              \
                tg = fmaf(w0s[mm].z, (XV), tg);                              \
                to = fmaf(w0s[mm].w, (XV), to);                              \
            }                                                                \
            const float ei = __builtin_amdgcn_exp2f(ti);                     \
            const float ef = __builtin_amdgcn_exp2f(tf);                     \
            const float eg = __builtin_amdgcn_exp2f(tg);                     \
            const float eo = __builtin_amdgcn_exp2f(to);                     \
            const float ig = (eg - 1.f) *                                    \
                __builtin_amdgcn_rcpf((1.f + ei) * (1.f + eg));              \
            const float ff = __builtin_amdgcn_rcpf(1.f + ef);                \
            cst[mm] = fmaf(ff, cst[mm], ig);                                 \
            const float tc = fminf(2.f * L2E * cst[mm], 60.f);               \
            const float ec = __builtin_amdgcn_exp2f(tc);                     \
            hn[mm] = (ec - 1.f) *                                            \
                __builtin_amdgcn_rcpf((1.f + eo) * (1.f + ec));              \
        }                                                                    \
    } while (0)

    const int NIT = T_STEPS + 3;      // 2051
    int sw = 0, sp = 2;               // write slot n%3, read slot (n-1)%3
    for (int n = 0; n < NIT; ++n) {
        f32x4 acc[2];
        float hn[2];
        if (lay == 0) {
            // ========== L0(t=n): gates = Whh0 @ h0(n-1) + Wih0*x + b ======
            if (n < T_STEPS) {
                const int tn = (n + 1 < T_STEPS) ? n + 1 : T_STEPS - 1;
                const float xn = x[tn * NBATCH + b0 + b];   // prefetch
                const f16x8 hb0 = hH[sp][0][l];
#pragma unroll
                for (int mm = 0; mm < 2; ++mm) {
                    f32x4 z = {0.f, 0.f, 0.f, 0.f};
                    acc[mm] = __builtin_amdgcn_mfma_f32_16x16x32_f16(Fh[mm], hb0, z, 0, 0, 0);
                }
                ACT2(1, xv);
                reinterpret_cast<unsigned*>(&hH[sw][0][l])[q] = pk2(hn[0], hn[1]);
                xv = xn;
            }
        } else if (lay == 1) {
            // ====== L1(t=n-1): gates = Wih1 @ h0(n-1) + Whh1 @ h1(n-2) ====
            if (n >= 1 && n <= T_STEPS) {
                const f16x8 hb0 = hH[sp][0][l];
                const f16x8 hb1 = hH[sp][1][l];
#pragma unroll
                for (int mm = 0; mm < 2; ++mm) {
                    f32x4 z = {0.f, 0.f, 0.f, 0.f};
                    z       = __builtin_amdgcn_mfma_f32_16x16x32_f16(Fi[mm], hb0, z, 0, 0, 0);
                    acc[mm] = __builtin_amdgcn_mfma_f32_16x16x32_f16(Fh[mm], hb1, z, 0, 0, 0);
                }
                ACT2(0, 0.f);
                reinterpret_cast<unsigned*>(&hH[sw][1][l])[q] = pk2(hn[0], hn[1]);
            }
        } else {
            // == L2(t=n-2): gates = Wih2 @ h1(n-2) + Whh2 @ h2(n-3); FC ====
            // q3 first: store out[t=n-3] from FCpart(n-1) + vprev(n-1)
            if (q == 3 && n >= 3 && l < 16)
                out[(n - 3) * NBATCH + b0 + l] =
                    FCpart[sp][0][l] + FCpart[sp][1][l] + FCpart[sp][2][l]
                    + vprev + bfc0;
            if (n >= 2 && n <= T_STEPS + 1) {
                const f16x8 hb1 = hH[sp][1][l];
                const f16x8 hb2 = hH[sp][2][l];
#pragma unroll
                for (int mm = 0; mm < 2; ++mm) {
                    f32x4 z = {0.f, 0.f, 0.f, 0.f};
                    z       = __builtin_amdgcn_mfma_f32_16x16x32_f16(Fi[mm], hb1, z, 0, 0, 0);
                    acc[mm] = __builtin_amdgcn_mfma_f32_16x16x32_f16(Fh[mm], hb2, z, 0, 0, 0);
                }
                ACT2(0, 0.f);
                reinterpret_cast<unsigned*>(&hH[sw][2][l])[q] = pk2(hn[0], hn[1]);
                float v = fmaf(wfc_r[0], hn[0], wfc_r[1] * hn[1]);
                v += __shfl_xor(v, 16);
                v += __shfl_xor(v, 32);
                if (q < 3) { if (l < 16) FCpart[sw][q][l] = v; }
                else       { vprev = v; }
            }
        }

        sync_lds();                   // reads of slot sp complete (lgkmcnt);
                                      // slot sp is rewritten 2 barriers later
        sp = sw; sw = (sw == 2) ? 0 : sw + 1;
    }
#undef ACT2
}

extern "C" void kernel_launch(void* const* d_in, const int* in_sizes, int n_in,
                              void* d_out, int out_size, void* d_ws, size_t ws_size,
                              hipStream_t stream)
{
    const float* x    = (const float*)d_in[0];
    const float* Wih0 = (const float*)d_in[1];
    const float* Whh0 = (const float*)d_in[2];
    const float* bih0 = (const float*)d_in[3];
    const float* bhh0 = (const float*)d_in[4];
    const float* Wih1 = (const float*)d_in[5];
    const float* Whh1 = (const float*)d_in[6];
    const float* bih1 = (const float*)d_in[7];
    const float* bhh1 = (const float*)d_in[8];
    const float* Wih2 = (const float*)d_in[9];
    const float* Whh2 = (const float*)d_in[10];
    const float* bih2 = (const float*)d_in[11];
    const float* bhh2 = (const float*)d_in[12];
    const float* Wfc  = (const float*)d_in[13];
    const float* bfc  = (const float*)d_in[14];
    float* out        = (float*)d_out;

    lstm3_ws12q_kernel<<<dim3(NBATCH / 16), dim3(768), 0, stream>>>(
        x, Wih0, Whh0, bih0, bhh0,
        Wih1, Whh1, bih1, bhh1,
        Wih2, Whh2, bih2, bhh2,
        Wfc, bfc, out);
}